// Round 4
// baseline (7961.884 us; speedup 1.0000x reference)
//
#include <hip/hip_runtime.h>
#include <hip/hip_bf16.h>

#define SEQ 2048
#define NB  64

typedef _Float16 f16x8 __attribute__((ext_vector_type(8)));
typedef _Float16 f16x4 __attribute__((ext_vector_type(4)));
typedef float    f32x4 __attribute__((ext_vector_type(4)));

__device__ __forceinline__ float fast_sigmoid(float x) {
    float e = __builtin_amdgcn_exp2f(-1.4426950408889634f * x);
    return __builtin_amdgcn_rcpf(1.f + e);
}
__device__ __forceinline__ float fast_tanh(float x) {
    float e = __builtin_amdgcn_exp2f(2.8853900817779268f * x);
    return fmaf(-2.f, __builtin_amdgcn_rcpf(1.f + e), 1.f);
}

// Split f32 -> (hi, lo) f16 pair: hi+lo carries ~22 mantissa bits.
__global__ __launch_bounds__(256) void split_f32(
    const float* __restrict__ s, _Float16* __restrict__ hi,
    _Float16* __restrict__ lo, int n)
{
    int i = blockIdx.x * 256 + threadIdx.x;
    if (i < n) {
        float v = s[i];
        _Float16 h = (_Float16)v;
        hi[i] = h;
        lo[i] = (_Float16)(v - (float)h);
    }
}

// gx fragment layout (per chunk step s):
//   off = s*65536 + (dir*4 + bg16)*8192 + gt*256 + lane*4 + reg   (f32)
// where bg16 = 16-batch group (0..3), gt = gate tile (0..31, 16 gates each),
// lane = MFMA lane, reg = C-frag register. This is exactly the 16x16x32 MFMA
// C layout (n = gt*16 + (lane&15), m(batch) = bg16*16 + (lane>>4)*4 + reg),
// so the rec kernel can load it straight into its accumulator init.

// ---------------------------------------------------------------------------
// Layer-0 input GEMM (K=64). A = x (f32, split on the fly), W pre-split f16.
// grid = (8, Tc, 2); wave = one 16(M)x64(N) tile.
// ---------------------------------------------------------------------------
__global__ __launch_bounds__(256) void gemm0(
    const float* __restrict__ x,
    const _Float16* __restrict__ whi_f, const _Float16* __restrict__ wlo_f,
    const _Float16* __restrict__ whi_r, const _Float16* __restrict__ wlo_r,
    const float* __restrict__ bf_, const float* __restrict__ br_,
    float* __restrict__ gx, int tq0)
{
    const int lane = threadIdx.x & 63, wave = threadIdx.x >> 6;
    const int dir  = blockIdx.z;
    const _Float16* Whi = dir ? whi_r : whi_f;
    const _Float16* Wlo = dir ? wlo_r : wlo_f;
    const float* bias   = dir ? br_   : bf_;
    const int s   = blockIdx.y;
    const int t   = dir ? (SEQ - 1 - tq0 - s) : (tq0 + s);
    const int n0  = blockIdx.x * 64;
    const int col = lane & 15, kg = lane >> 4;

    f16x8 Bhi[4][2], Blo[4][2];
    #pragma unroll
    for (int nt = 0; nt < 4; ++nt)
        #pragma unroll
        for (int ks = 0; ks < 2; ++ks) {
            size_t idx = (size_t)(n0 + nt*16 + col) * 64 + ks*32 + kg*8;
            Bhi[nt][ks] = *(const f16x8*)(Whi + idx);
            Blo[nt][ks] = *(const f16x8*)(Wlo + idx);
        }
    f32x4 acc[4] = {{0,0,0,0},{0,0,0,0},{0,0,0,0},{0,0,0,0}};
    #pragma unroll
    for (int ks = 0; ks < 2; ++ks) {
        const float* ar = x + ((size_t)t*NB + wave*16 + col) * 64 + ks*32 + kg*8;
        float4 a0 = *(const float4*)ar;
        float4 a1 = *(const float4*)(ar + 4);
        f16x8 ahi, alo;
        float av[8] = {a0.x,a0.y,a0.z,a0.w,a1.x,a1.y,a1.z,a1.w};
        #pragma unroll
        for (int e = 0; e < 8; ++e) {
            _Float16 h = (_Float16)av[e];
            ahi[e] = h; alo[e] = (_Float16)(av[e] - (float)h);
        }
        #pragma unroll
        for (int nt = 0; nt < 4; ++nt) {
            acc[nt] = __builtin_amdgcn_mfma_f32_16x16x32_f16(ahi, Bhi[nt][ks], acc[nt], 0,0,0);
            acc[nt] = __builtin_amdgcn_mfma_f32_16x16x32_f16(ahi, Blo[nt][ks], acc[nt], 0,0,0);
            acc[nt] = __builtin_amdgcn_mfma_f32_16x16x32_f16(alo, Bhi[nt][ks], acc[nt], 0,0,0);
        }
    }
    #pragma unroll
    for (int nt = 0; nt < 4; ++nt) {
        const int n = n0 + nt*16 + col;
        const float bv = bias[n];
        f32x4 v = {acc[nt][0]+bv, acc[nt][1]+bv, acc[nt][2]+bv, acc[nt][3]+bv};
        size_t fi = (size_t)s*65536 + (dir*4 + wave)*8192 + (blockIdx.x*4 + nt)*256 + lane*4;
        *(f32x4*)(gx + fi) = v;
    }
}

// ---------------------------------------------------------------------------
// Layer-1 input GEMM (K=256). A = h0 pre-split f16 hi/lo. grid = (8, Tc, 2).
// ---------------------------------------------------------------------------
template<int SPLIT_A>
__global__ __launch_bounds__(256) void gemm1(
    const _Float16* __restrict__ Ahi, const _Float16* __restrict__ Alo,
    const _Float16* __restrict__ whi_f, const _Float16* __restrict__ wlo_f,
    const _Float16* __restrict__ whi_r, const _Float16* __restrict__ wlo_r,
    const float* __restrict__ bf_, const float* __restrict__ br_,
    float* __restrict__ gx, int tq0)
{
    const int lane = threadIdx.x & 63, wave = threadIdx.x >> 6;
    const int dir  = blockIdx.z;
    const _Float16* Whi = dir ? whi_r : whi_f;
    const _Float16* Wlo = dir ? wlo_r : wlo_f;
    const float* bias   = dir ? br_   : bf_;
    const int wm = wave >> 1, wn = wave & 1;
    const int s  = blockIdx.y;
    const int t  = dir ? (SEQ - 1 - tq0 - s) : (tq0 + s);
    const int n0 = blockIdx.x * 64 + wn * 32;
    const int col = lane & 15, kg = lane >> 4;

    f16x8 Bhi[2][8], Blo[2][8];
    #pragma unroll
    for (int nt = 0; nt < 2; ++nt)
        #pragma unroll
        for (int ks = 0; ks < 8; ++ks) {
            size_t idx = (size_t)(n0 + nt*16 + col) * 256 + ks*32 + kg*8;
            Bhi[nt][ks] = *(const f16x8*)(Whi + idx);
            Blo[nt][ks] = *(const f16x8*)(Wlo + idx);
        }
    f32x4 acc[2][2] = {{{0,0,0,0},{0,0,0,0}},{{0,0,0,0},{0,0,0,0}}};
    #pragma unroll
    for (int ks = 0; ks < 8; ++ks) {
        #pragma unroll
        for (int mt = 0; mt < 2; ++mt) {
            const size_t arow = (size_t)t*NB + wm*32 + mt*16 + col;
            f16x8 ahi = *(const f16x8*)(Ahi + arow*256 + ks*32 + kg*8);
            f16x8 alo;
            if constexpr (SPLIT_A) alo = *(const f16x8*)(Alo + arow*256 + ks*32 + kg*8);
            #pragma unroll
            for (int nt = 0; nt < 2; ++nt) {
                acc[mt][nt] = __builtin_amdgcn_mfma_f32_16x16x32_f16(ahi, Bhi[nt][ks], acc[mt][nt], 0,0,0);
                acc[mt][nt] = __builtin_amdgcn_mfma_f32_16x16x32_f16(ahi, Blo[nt][ks], acc[mt][nt], 0,0,0);
                if constexpr (SPLIT_A)
                    acc[mt][nt] = __builtin_amdgcn_mfma_f32_16x16x32_f16(alo, Bhi[nt][ks], acc[mt][nt], 0,0,0);
            }
        }
    }
    #pragma unroll
    for (int mt = 0; mt < 2; ++mt)
        #pragma unroll
        for (int nt = 0; nt < 2; ++nt) {
            const int n = n0 + nt*16 + col;
            const float bv = bias[n];
            f32x4 v = {acc[mt][nt][0]+bv, acc[mt][nt][1]+bv, acc[mt][nt][2]+bv, acc[mt][nt][3]+bv};
            size_t fi = (size_t)s*65536 + (dir*4 + (wm*2+mt))*8192
                      + (blockIdx.x*4 + wn*2 + nt)*256 + lane*4;
            *(f32x4*)(gx + fi) = v;
        }
}

// ---------------------------------------------------------------------------
// MFMA recurrence. Grid (8 bg, 2 dir) = 16 WGs, 512 thr = 8 waves.
// Wave w owns, for each gate type T (i,f,g,o), gate tile gt = 8T + w,
// i.e. gate columns n = 128T + 16w + col  ->  k-index kidx = 16w + col.
// M-tile = 16 (8 real batch rows + 8 zero rows). K = 128 (4 MFMA k-slices).
// 3-term split f16: Whi*hhi + Whi*hlo + Wlo*hhi  (f32-quality).
// h exchanged via XOR-swizzled LDS double buffer; c stays in registers.
// Epilogue is lane-local: acc[0..3][r] = preact(i,f,g,o) at (m=kg*4+r, kidx).
// ---------------------------------------------------------------------------
template<int OMODE>   // 0: write h as f16 hi+lo (feeds gemm1); 1: hi only
__global__ __launch_bounds__(512, 2) void lstm_rec2(
    const float* __restrict__ gx,      // frag layout, chunk-local
    const float* __restrict__ Whf, const float* __restrict__ Whr,
    _Float16* __restrict__ o1, _Float16* __restrict__ o2,  // [SEQ*NB][256]
    float* __restrict__ state,         // [dir][bg][ h:8x128 | c:8x128 ] f32
    int tq0, int steps, int first)
{
    const int bg  = blockIdx.x;        // 8 batch rows per WG
    const int dir = blockIdx.y;
    const float* Wh = dir ? Whr : Whf;
    const int tid  = threadIdx.x;
    const int w    = tid >> 6;
    const int lane = tid & 63;
    const int col  = lane & 15;
    const int kg   = lane >> 4;
    const int kidx = 16*w + col;

    // B fragments: B[n][k], n = gt*16+col, k = ks*32 + kg*8 + e
    f16x8 Bhi[4][4], Blo[4][4];
    #pragma unroll
    for (int T = 0; T < 4; ++T) {
        const float* wr = Wh + (size_t)((8*T + w)*16 + col) * 128;
        #pragma unroll
        for (int ks = 0; ks < 4; ++ks) {
            const float* p4 = wr + ks*32 + kg*8;
            float4 a0 = *(const float4*)p4, a1 = *(const float4*)(p4+4);
            float av[8] = {a0.x,a0.y,a0.z,a0.w,a1.x,a1.y,a1.z,a1.w};
            f16x8 hi, lo;
            #pragma unroll
            for (int e = 0; e < 8; ++e) {
                _Float16 h = (_Float16)av[e];
                hi[e] = h; lo[e] = (_Float16)(av[e] - (float)h);
            }
            Bhi[T][ks] = hi; Blo[T][ks] = lo;
        }
    }

    // h double buffer: [phase][16 rows][128 k] f16, XOR-swizzled.
    // element index: el = (m*128 + k) ^ ((m&7)<<3); 16B unit: el>>3.
    __shared__ f16x8 Hhi[2][256];
    __shared__ f16x8 Hlo[2][256];
    for (int i = tid; i < 512; i += 512) { Hhi[0][0]; }  // (no-op, keep layout)
    {   // zero both buffers (incl. pad rows 8..15 which stay zero forever)
        f16x8 z = {};
        if (tid < 512) { Hhi[tid>>8][tid&255] = z; Hlo[tid>>8][tid&255] = z; }
    }
    __syncthreads();

    float cr[4] = {0,0,0,0};
    float hr[4] = {0,0,0,0};
    float* stbase = state + ((size_t)dir*8 + bg) * 2048;
    if (!first && kg < 2) {
        #pragma unroll
        for (int r = 0; r < 4; ++r) {
            const int m = kg*4 + r;
            float hv = stbase[m*128 + kidx];
            cr[r] = stbase[1024 + m*128 + kidx];
            hr[r] = hv;
            _Float16 hhi = (_Float16)hv;
            _Float16 hlo = (_Float16)(hv - (float)hhi);
            int el = (m*128 + kidx) ^ ((m&7)<<3);
            ((_Float16*)Hhi[0])[el] = hhi;
            ((_Float16*)Hlo[0])[el] = hlo;
        }
    }
    __syncthreads();

    // gx fragment addressing for this lane (active half: kg<2)
    const int lane2 = (kg + 2*(bg&1))*16 + col;      // row inside the 16-batch tile
    const int bgq   = bg >> 1;                       // 16-batch group
    const size_t gxo = (size_t)(dir*4 + bgq)*8192 + (size_t)lane2*4;

    f32x4 gcur[4] = {{0,0,0,0},{0,0,0,0},{0,0,0,0},{0,0,0,0}};
    if (kg < 2) {
        #pragma unroll
        for (int T = 0; T < 4; ++T)
            gcur[T] = *(const f32x4*)(gx + gxo + (8*T + w)*256);
    }

    int p = 0;
    for (int step = 0; step < steps; ++step) {
        // A fragments from LDS (hi & lo), swizzled 16B reads
        f16x8 Ahi[4], Alo[4];
        #pragma unroll
        for (int ks = 0; ks < 4; ++ks) {
            int idx = (col*16 + ks*4 + kg) ^ (col & 7);
            Ahi[ks] = Hhi[p][idx];
            Alo[ks] = Hlo[p][idx];
        }
        // prefetch next step's gx fragments (hidden under MFMA)
        f32x4 gnx[4] = {{0,0,0,0},{0,0,0,0},{0,0,0,0},{0,0,0,0}};
        if (step + 1 < steps && kg < 2) {
            const size_t b = gxo + (size_t)(step+1)*65536;
            #pragma unroll
            for (int T = 0; T < 4; ++T)
                gnx[T] = *(const f32x4*)(gx + b + (8*T + w)*256);
        }
        // MFMA: acc init = gx (C-in), 3-term split over 4 k-slices
        f32x4 acc[4];
        #pragma unroll
        for (int T = 0; T < 4; ++T) acc[T] = gcur[T];
        #pragma unroll
        for (int ks = 0; ks < 4; ++ks)
            #pragma unroll
            for (int T = 0; T < 4; ++T) {
                acc[T] = __builtin_amdgcn_mfma_f32_16x16x32_f16(Ahi[ks], Bhi[T][ks], acc[T], 0,0,0);
                acc[T] = __builtin_amdgcn_mfma_f32_16x16x32_f16(Alo[ks], Bhi[T][ks], acc[T], 0,0,0);
                acc[T] = __builtin_amdgcn_mfma_f32_16x16x32_f16(Ahi[ks], Blo[T][ks], acc[T], 0,0,0);
            }
        // epilogue: lane-local gates -> c,h; publish h to LDS[p^1] and global
        if (kg < 2) {
            const int t = dir ? (SEQ-1 - tq0 - step) : (tq0 + step);
            #pragma unroll
            for (int r = 0; r < 4; ++r) {
                float iv = fast_sigmoid(acc[0][r]);
                float fv = fast_sigmoid(acc[1][r]);
                float gv = fast_tanh(acc[2][r]);
                float ov = fast_sigmoid(acc[3][r]);
                float cv = fmaf(fv, cr[r], iv * gv);
                cr[r] = cv;
                float hv = ov * fast_tanh(cv);
                hr[r] = hv;
                _Float16 hhi = (_Float16)hv;
                _Float16 hlo = (_Float16)(hv - (float)hhi);
                const int m = kg*4 + r;
                int el = (m*128 + kidx) ^ ((m&7)<<3);
                ((_Float16*)Hhi[p^1])[el] = hhi;
                ((_Float16*)Hlo[p^1])[el] = hlo;
                size_t oi = ((size_t)t*NB + (bg*8 + m))*256 + dir*128 + kidx;
                o1[oi] = hhi;
                if constexpr (OMODE == 0) o2[oi] = hlo;
            }
        }
        __syncthreads();
        p ^= 1;
        #pragma unroll
        for (int T = 0; T < 4; ++T) gcur[T] = gnx[T];
    }
    if (kg < 2) {
        #pragma unroll
        for (int r = 0; r < 4; ++r) {
            const int m = kg*4 + r;
            stbase[m*128 + kidx] = hr[r];
            stbase[1024 + m*128 + kidx] = cr[r];
        }
    }
}

// ---------------------------------------------------------------------------
// Head: y[m] = sum_j out1[m][j]*w_out[j] + b_out. One wave per row.
// ---------------------------------------------------------------------------
__global__ __launch_bounds__(256) void final_lin(
    const _Float16* __restrict__ out1,
    const float* __restrict__ wout, const float* __restrict__ bout,
    float* __restrict__ y)
{
    const int lane = threadIdx.x & 63;
    const int wave = threadIdx.x >> 6;
    const int row  = blockIdx.x * 4 + wave;
    f16x4 u = *(const f16x4*)(out1 + (size_t)row*256 + lane*4);
    float4 wv = *(const float4*)(wout + lane*4);
    float s = (float)u[0]*wv.x + (float)u[1]*wv.y + (float)u[2]*wv.z + (float)u[3]*wv.w;
    #pragma unroll
    for (int off = 32; off > 0; off >>= 1) s += __shfl_down(s, off, 64);
    if (lane == 0) y[row] = s + bout[0];
}

extern "C" void kernel_launch(void* const* d_in, const int* in_sizes, int n_in,
                              void* d_out, int out_size, void* d_ws, size_t ws_size,
                              hipStream_t stream) {
    const float* x      = (const float*)d_in[0];
    const float* wih_f0 = (const float*)d_in[1];
    const float* whh_f0 = (const float*)d_in[2];
    const float* b_f0   = (const float*)d_in[3];
    const float* wih_r0 = (const float*)d_in[4];
    const float* whh_r0 = (const float*)d_in[5];
    const float* b_r0   = (const float*)d_in[6];
    const float* wih_f1 = (const float*)d_in[7];
    const float* whh_f1 = (const float*)d_in[8];
    const float* b_f1   = (const float*)d_in[9];
    const float* wih_r1 = (const float*)d_in[10];
    const float* whh_r1 = (const float*)d_in[11];
    const float* b_r1   = (const float*)d_in[12];
    const float* w_out  = (const float*)d_in[13];
    const float* b_out  = (const float*)d_in[14];

    const size_t w0N = 512*64, w1N = (size_t)512*256;
    const size_t w0B = w0N*2, w1B = w1N*2;
    const size_t stB = 2*8*2048*4;               // 128 KB rec state
    const size_t hB  = (size_t)SEQ*NB*256*2;     // 67.1 MB per f16 h-buffer
    const size_t fixedB = 4*w0B + 4*w1B + stB;

    const int cand[7] = {2048, 1024, 512, 256, 128, 64, 32};
    int Tc = 0; int tierA = 1;
    for (int i = 0; i < 7 && !Tc; ++i)
        if (fixedB + 3*hB + (size_t)cand[i]*NB*1024*4 <= ws_size) Tc = cand[i];
    if (!Tc) {
        tierA = 0;
        for (int i = 0; i < 7 && !Tc; ++i)
            if (fixedB + 2*hB + (size_t)cand[i]*NB*1024*4 <= ws_size) Tc = cand[i];
        if (!Tc) Tc = 32;
    }
    const int nq = SEQ / Tc;

    char* p = (char*)d_ws;
    _Float16* whi0f = (_Float16*)p; p += w0B;
    _Float16* wlo0f = (_Float16*)p; p += w0B;
    _Float16* whi0r = (_Float16*)p; p += w0B;
    _Float16* wlo0r = (_Float16*)p; p += w0B;
    _Float16* whi1f = (_Float16*)p; p += w1B;
    _Float16* wlo1f = (_Float16*)p; p += w1B;
    _Float16* whi1r = (_Float16*)p; p += w1B;
    _Float16* wlo1r = (_Float16*)p; p += w1B;
    float*    state = (float*)p;    p += stB;
    _Float16* out1  = (_Float16*)p; p += hB;
    _Float16* h0hi  = (_Float16*)p; p += hB;
    _Float16* h0lo  = (_Float16*)p; if (tierA) p += hB;
    float*    gx    = (float*)p;

    split_f32<<<(int)((w0N+255)/256), 256, 0, stream>>>(wih_f0, whi0f, wlo0f, (int)w0N);
    split_f32<<<(int)((w0N+255)/256), 256, 0, stream>>>(wih_r0, whi0r, wlo0r, (int)w0N);
    split_f32<<<(int)((w1N+255)/256), 256, 0, stream>>>(wih_f1, whi1f, wlo1f, (int)w1N);
    split_f32<<<(int)((w1N+255)/256), 256, 0, stream>>>(wih_r1, whi1r, wlo1r, (int)w1N);

    for (int q = 0; q < nq; ++q) {
        gemm0<<<dim3(8, Tc, 2), 256, 0, stream>>>(x, whi0f, wlo0f, whi0r, wlo0r,
                                                  b_f0, b_r0, gx, q*Tc);
        if (tierA)
            lstm_rec2<0><<<dim3(8,2), 512, 0, stream>>>(gx, whh_f0, whh_r0, h0hi, h0lo,
                                                        state, q*Tc, Tc, q==0);
        else
            lstm_rec2<1><<<dim3(8,2), 512, 0, stream>>>(gx, whh_f0, whh_r0, h0hi, nullptr,
                                                        state, q*Tc, Tc, q==0);
    }
    for (int q = 0; q < nq; ++q) {
        if (tierA)
            gemm1<1><<<dim3(8, Tc, 2), 256, 0, stream>>>(h0hi, h0lo, whi1f, wlo1f, whi1r, wlo1r,
                                                         b_f1, b_r1, gx, q*Tc);
        else
            gemm1<0><<<dim3(8, Tc, 2), 256, 0, stream>>>(h0hi, h0hi, whi1f, wlo1f, whi1r, wlo1r,
                                                         b_f1, b_r1, gx, q*Tc);
        lstm_rec2<1><<<dim3(8,2), 512, 0, stream>>>(gx, whh_f1, whh_r1, out1, nullptr,
                                                    state, q*Tc, Tc, q==0);
    }
    final_lin<<<SEQ*NB/4, 256, 0, stream>>>(out1, w_out, b_out, (float*)d_out);
}

// Round 5
// 6885.612 us; speedup vs baseline: 1.1563x; 1.1563x over previous
//
#include <hip/hip_runtime.h>
#include <hip/hip_bf16.h>

#define SEQ 2048
#define NB  64

typedef _Float16 f16x8 __attribute__((ext_vector_type(8)));
typedef _Float16 f16x4 __attribute__((ext_vector_type(4)));
typedef float    f32x4 __attribute__((ext_vector_type(4)));

__device__ __forceinline__ float fast_sigmoid(float x) {
    float e = __builtin_amdgcn_exp2f(-1.4426950408889634f * x);
    return __builtin_amdgcn_rcpf(1.f + e);
}
__device__ __forceinline__ float fast_tanh(float x) {
    float e = __builtin_amdgcn_exp2f(2.8853900817779268f * x);
    return fmaf(-2.f, __builtin_amdgcn_rcpf(1.f + e), 1.f);
}

// Split f32 -> (hi, lo) f16 pair: hi+lo carries ~22 mantissa bits.
__global__ __launch_bounds__(256) void split_f32(
    const float* __restrict__ s, _Float16* __restrict__ hi,
    _Float16* __restrict__ lo, int n)
{
    int i = blockIdx.x * 256 + threadIdx.x;
    if (i < n) {
        float v = s[i];
        _Float16 h = (_Float16)v;
        hi[i] = h;
        lo[i] = (_Float16)(v - (float)h);
    }
}

// gx fragment layout (per chunk step s):
//   off = s*65536 + (dir*4 + bg16)*8192 + gt*256 + lane*4 + reg   (f32)
// bg16 = 16-batch group (0..3), gt = gate tile (0..31, 16 gates each).
// Exactly the 16x16x32 MFMA C layout: n = gt*16+(lane&15), m = bg16*16+(lane>>4)*4+reg.

// ---------------------------------------------------------------------------
// Layer-0 input GEMM (K=64). B streamed in k-loop (no big frag arrays).
// grid = (8, Tc, 2); wave = one 16(M)x64(N) tile.
// ---------------------------------------------------------------------------
__global__ __launch_bounds__(256) void gemm0(
    const float* __restrict__ x,
    const _Float16* __restrict__ whi_f, const _Float16* __restrict__ wlo_f,
    const _Float16* __restrict__ whi_r, const _Float16* __restrict__ wlo_r,
    const float* __restrict__ bf_, const float* __restrict__ br_,
    float* __restrict__ gx, int tq0)
{
    const int lane = threadIdx.x & 63, wave = threadIdx.x >> 6;
    const int dir  = blockIdx.z;
    const _Float16* Whi = dir ? whi_r : whi_f;
    const _Float16* Wlo = dir ? wlo_r : wlo_f;
    const float* bias   = dir ? br_   : bf_;
    const int s   = blockIdx.y;
    const int t   = dir ? (SEQ - 1 - tq0 - s) : (tq0 + s);
    const int n0  = blockIdx.x * 64;
    const int col = lane & 15, kg = lane >> 4;

    f32x4 acc[4] = {{0,0,0,0},{0,0,0,0},{0,0,0,0},{0,0,0,0}};
    #pragma unroll
    for (int ks = 0; ks < 2; ++ks) {
        const float* ar = x + ((size_t)t*NB + wave*16 + col) * 64 + ks*32 + kg*8;
        float4 a0 = *(const float4*)ar;
        float4 a1 = *(const float4*)(ar + 4);
        f16x8 ahi, alo;
        float av[8] = {a0.x,a0.y,a0.z,a0.w,a1.x,a1.y,a1.z,a1.w};
        #pragma unroll
        for (int e = 0; e < 8; ++e) {
            _Float16 h = (_Float16)av[e];
            ahi[e] = h; alo[e] = (_Float16)(av[e] - (float)h);
        }
        #pragma unroll
        for (int nt = 0; nt < 4; ++nt) {
            size_t idx = (size_t)(n0 + nt*16 + col) * 64 + ks*32 + kg*8;
            f16x8 bhi = *(const f16x8*)(Whi + idx);
            f16x8 blo = *(const f16x8*)(Wlo + idx);
            acc[nt] = __builtin_amdgcn_mfma_f32_16x16x32_f16(ahi, bhi, acc[nt], 0,0,0);
            acc[nt] = __builtin_amdgcn_mfma_f32_16x16x32_f16(ahi, blo, acc[nt], 0,0,0);
            acc[nt] = __builtin_amdgcn_mfma_f32_16x16x32_f16(alo, bhi, acc[nt], 0,0,0);
        }
    }
    #pragma unroll
    for (int nt = 0; nt < 4; ++nt) {
        const int n = n0 + nt*16 + col;
        const float bv = bias[n];
        f32x4 v = {acc[nt][0]+bv, acc[nt][1]+bv, acc[nt][2]+bv, acc[nt][3]+bv};
        size_t fi = (size_t)s*65536 + (size_t)(dir*4 + wave)*8192
                  + (size_t)(blockIdx.x*4 + nt)*256 + lane*4;
        *(f32x4*)(gx + fi) = v;
    }
}

// ---------------------------------------------------------------------------
// Layer-1 input GEMM (K=256). A = h0 pre-split f16 hi/lo. B streamed in k-loop.
// grid = (8, Tc, 2); wave = 32Mx32N.
// ---------------------------------------------------------------------------
template<int SPLIT_A>
__global__ __launch_bounds__(256) void gemm1(
    const _Float16* __restrict__ Ahi, const _Float16* __restrict__ Alo,
    const _Float16* __restrict__ whi_f, const _Float16* __restrict__ wlo_f,
    const _Float16* __restrict__ whi_r, const _Float16* __restrict__ wlo_r,
    const float* __restrict__ bf_, const float* __restrict__ br_,
    float* __restrict__ gx, int tq0)
{
    const int lane = threadIdx.x & 63, wave = threadIdx.x >> 6;
    const int dir  = blockIdx.z;
    const _Float16* Whi = dir ? whi_r : whi_f;
    const _Float16* Wlo = dir ? wlo_r : wlo_f;
    const float* bias   = dir ? br_   : bf_;
    const int wm = wave >> 1, wn = wave & 1;
    const int s  = blockIdx.y;
    const int t  = dir ? (SEQ - 1 - tq0 - s) : (tq0 + s);
    const int n0 = blockIdx.x * 64 + wn * 32;
    const int col = lane & 15, kg = lane >> 4;

    f32x4 acc[2][2] = {{{0,0,0,0},{0,0,0,0}},{{0,0,0,0},{0,0,0,0}}};
    #pragma unroll
    for (int ks = 0; ks < 8; ++ks) {
        f16x8 ahi[2], alo[2];
        #pragma unroll
        for (int mt = 0; mt < 2; ++mt) {
            const size_t arow = (size_t)t*NB + wm*32 + mt*16 + col;
            ahi[mt] = *(const f16x8*)(Ahi + arow*256 + ks*32 + kg*8);
            if constexpr (SPLIT_A) alo[mt] = *(const f16x8*)(Alo + arow*256 + ks*32 + kg*8);
        }
        #pragma unroll
        for (int nt = 0; nt < 2; ++nt) {
            size_t idx = (size_t)(n0 + nt*16 + col) * 256 + ks*32 + kg*8;
            f16x8 bhi = *(const f16x8*)(Whi + idx);
            f16x8 blo = *(const f16x8*)(Wlo + idx);
            #pragma unroll
            for (int mt = 0; mt < 2; ++mt) {
                acc[mt][nt] = __builtin_amdgcn_mfma_f32_16x16x32_f16(ahi[mt], bhi, acc[mt][nt], 0,0,0);
                acc[mt][nt] = __builtin_amdgcn_mfma_f32_16x16x32_f16(ahi[mt], blo, acc[mt][nt], 0,0,0);
                if constexpr (SPLIT_A)
                    acc[mt][nt] = __builtin_amdgcn_mfma_f32_16x16x32_f16(alo[mt], bhi, acc[mt][nt], 0,0,0);
            }
        }
    }
    #pragma unroll
    for (int mt = 0; mt < 2; ++mt)
        #pragma unroll
        for (int nt = 0; nt < 2; ++nt) {
            const int n = n0 + nt*16 + col;
            const float bv = bias[n];
            f32x4 v = {acc[mt][nt][0]+bv, acc[mt][nt][1]+bv, acc[mt][nt][2]+bv, acc[mt][nt][3]+bv};
            size_t fi = (size_t)s*65536 + (size_t)(dir*4 + (wm*2+mt))*8192
                      + (size_t)(blockIdx.x*4 + wn*2 + nt)*256 + lane*4;
            *(f32x4*)(gx + fi) = v;
        }
}

// ---------------------------------------------------------------------------
// MFMA recurrence v3. Grid (4 bg, 2 dir) = 8 WGs, 512 thr = 8 waves.
// Full 16-batch M-tile per WG. Wave w: gate tiles gt = 8T+w (T=i,f,g,o),
// cell kidx = 16w+col. K=128 over 4 k-slices, 3-term split f16.
// Per step: ONE raw s_barrier with lgkmcnt(0) only — gx prefetch (2 deep)
// and h global stores stay in flight across barriers (no vmcnt drain).
// h exchanged via statically double-buffered XOR-swizzled LDS.
// ---------------------------------------------------------------------------
template<int OMODE>   // 0: write h as f16 hi+lo (feeds gemm1); 1: hi only
__global__ __launch_bounds__(512, 2) void lstm_rec3(
    const float* __restrict__ gx,      // frag layout, chunk-local, +2 steps pad
    const float* __restrict__ Whf, const float* __restrict__ Whr,
    _Float16* __restrict__ o1, _Float16* __restrict__ o2,  // [SEQ*NB][256]
    float* __restrict__ state,         // [dir][bg][ h:16x128 | c:16x128 ] f32
    int tq0, int steps, int first)
{
    const int bg  = blockIdx.x;        // 16 batch rows per WG
    const int dir = blockIdx.y;
    const float* Wh = dir ? Whr : Whf;
    const int tid  = threadIdx.x;
    const int w    = tid >> 6;
    const int lane = tid & 63;
    const int col  = lane & 15;
    const int kg   = lane >> 4;
    const int kidx = 16*w + col;

    // B fragments (weights, f32-split into f16 hi/lo): 4T x 4ks x 2
    f16x8 Bhi[4][4], Blo[4][4];
    #pragma unroll
    for (int T = 0; T < 4; ++T) {
        const float* wr = Wh + (size_t)((8*T + w)*16 + col) * 128;
        #pragma unroll
        for (int ks = 0; ks < 4; ++ks) {
            const float* p4 = wr + ks*32 + kg*8;
            float4 a0 = *(const float4*)p4, a1 = *(const float4*)(p4+4);
            float av[8] = {a0.x,a0.y,a0.z,a0.w,a1.x,a1.y,a1.z,a1.w};
            f16x8 hi, lo;
            #pragma unroll
            for (int e = 0; e < 8; ++e) {
                _Float16 h = (_Float16)av[e];
                hi[e] = h; lo[e] = (_Float16)(av[e] - (float)h);
            }
            Bhi[T][ks] = hi; Blo[T][ks] = lo;
        }
    }

    // h tile 16x128 f16, XOR-swizzled in 16B units: unit(m,u) at m*16 + (u^m),
    // u = k>>3. Static double buffer A/B (no runtime phase index).
    __shared__ f16x8 HhiA[256], HloA[256], HhiB[256], HloB[256];

    float cr[4], hr[4];
    float* stbase = state + ((size_t)dir*4 + bg) * 4096;
    #pragma unroll
    for (int r = 0; r < 4; ++r) {
        const int m = kg*4 + r;
        float hv = first ? 0.f : stbase[m*128 + kidx];
        float cv = first ? 0.f : stbase[2048 + m*128 + kidx];
        hr[r] = hv; cr[r] = cv;
        _Float16 hhi = (_Float16)hv;
        _Float16 hlo = (_Float16)(hv - (float)hhi);
        const int el = m*128 + (((kidx>>3) ^ m) & 15)*8 + (kidx & 7);
        ((_Float16*)HhiA)[el] = hhi;
        ((_Float16*)HloA)[el] = hlo;
    }
    __syncthreads();

    const float* gxp = gx + (size_t)(dir*4 + bg)*8192 + (size_t)lane*4;

    // 2-deep gx prefetch in named register buffers (steps is even; gx has +2 pad)
    f32x4 gA[4], gB[4];
    #pragma unroll
    for (int T = 0; T < 4; ++T) {
        gA[T] = *(const f32x4*)(gxp + (8*T + w)*256);
        gB[T] = *(const f32x4*)(gxp + (8*T + w)*256 + 65536);
    }

    auto rec_step = [&](f32x4 (&G)[4], f16x8 (&RHI)[256], f16x8 (&RLO)[256],
                        f16x8 (&WHI)[256], f16x8 (&WLO)[256], int STEP) {
        // A fragments from LDS (swizzled, conflict-free b128 reads)
        f16x8 Ah[4], Al[4];
        #pragma unroll
        for (int ks = 0; ks < 4; ++ks) {
            const int u = col*16 + ((ks*4 + kg) ^ col);
            Ah[ks] = RHI[u];
            Al[ks] = RLO[u];
        }
        f32x4 acc0 = G[0], acc1 = G[1], acc2 = G[2], acc3 = G[3];
        // prefetch step+2 into the same named buffer (in flight across barriers)
        #pragma unroll
        for (int T = 0; T < 4; ++T)
            G[T] = *(const f32x4*)(gxp + (8*T + w)*256 + (size_t)(STEP + 2)*65536);
        #pragma unroll
        for (int ks = 0; ks < 4; ++ks) {
            acc0 = __builtin_amdgcn_mfma_f32_16x16x32_f16(Ah[ks], Bhi[0][ks], acc0, 0,0,0);
            acc0 = __builtin_amdgcn_mfma_f32_16x16x32_f16(Al[ks], Bhi[0][ks], acc0, 0,0,0);
            acc0 = __builtin_amdgcn_mfma_f32_16x16x32_f16(Ah[ks], Blo[0][ks], acc0, 0,0,0);
            acc1 = __builtin_amdgcn_mfma_f32_16x16x32_f16(Ah[ks], Bhi[1][ks], acc1, 0,0,0);
            acc1 = __builtin_amdgcn_mfma_f32_16x16x32_f16(Al[ks], Bhi[1][ks], acc1, 0,0,0);
            acc1 = __builtin_amdgcn_mfma_f32_16x16x32_f16(Ah[ks], Blo[1][ks], acc1, 0,0,0);
            acc2 = __builtin_amdgcn_mfma_f32_16x16x32_f16(Ah[ks], Bhi[2][ks], acc2, 0,0,0);
            acc2 = __builtin_amdgcn_mfma_f32_16x16x32_f16(Al[ks], Bhi[2][ks], acc2, 0,0,0);
            acc2 = __builtin_amdgcn_mfma_f32_16x16x32_f16(Ah[ks], Blo[2][ks], acc2, 0,0,0);
            acc3 = __builtin_amdgcn_mfma_f32_16x16x32_f16(Ah[ks], Bhi[3][ks], acc3, 0,0,0);
            acc3 = __builtin_amdgcn_mfma_f32_16x16x32_f16(Al[ks], Bhi[3][ks], acc3, 0,0,0);
            acc3 = __builtin_amdgcn_mfma_f32_16x16x32_f16(Ah[ks], Blo[3][ks], acc3, 0,0,0);
        }
        const int t = dir ? (SEQ-1 - tq0 - STEP) : (tq0 + STEP);
        #pragma unroll
        for (int r = 0; r < 4; ++r) {
            float iv = fast_sigmoid(acc0[r]);
            float fv = fast_sigmoid(acc1[r]);
            float gv = fast_tanh(acc2[r]);
            float ov = fast_sigmoid(acc3[r]);
            float cv = fmaf(fv, cr[r], iv * gv);
            cr[r] = cv;
            float hv = ov * fast_tanh(cv);
            hr[r] = hv;
            _Float16 hhi = (_Float16)hv;
            _Float16 hlo = (_Float16)(hv - (float)hhi);
            const int m = kg*4 + r;
            const int el = m*128 + (((kidx>>3) ^ m) & 15)*8 + (kidx & 7);
            ((_Float16*)WHI)[el] = hhi;
            ((_Float16*)WLO)[el] = hlo;
            const size_t oi = ((size_t)t*NB + (bg*16 + m))*256 + dir*128 + kidx;
            o1[oi] = hhi;                      // fire-and-forget (no vmcnt drain)
            if constexpr (OMODE == 0) o2[oi] = hlo;
        }
        // LDS-only barrier: h published, global ops stay in flight
        asm volatile("s_waitcnt lgkmcnt(0)" ::: "memory");
        __builtin_amdgcn_s_barrier();
        asm volatile("" ::: "memory");
    };

    for (int step = 0; step < steps; step += 2) {
        rec_step(gA, HhiA, HloA, HhiB, HloB, step);
        rec_step(gB, HhiB, HloB, HhiA, HloA, step + 1);
    }

    #pragma unroll
    for (int r = 0; r < 4; ++r) {
        const int m = kg*4 + r;
        stbase[m*128 + kidx] = hr[r];
        stbase[2048 + m*128 + kidx] = cr[r];
    }
}

// ---------------------------------------------------------------------------
// Head: y[m] = sum_j out1[m][j]*w_out[j] + b_out. One wave per row.
// ---------------------------------------------------------------------------
__global__ __launch_bounds__(256) void final_lin(
    const _Float16* __restrict__ out1,
    const float* __restrict__ wout, const float* __restrict__ bout,
    float* __restrict__ y)
{
    const int lane = threadIdx.x & 63;
    const int wave = threadIdx.x >> 6;
    const int row  = blockIdx.x * 4 + wave;
    f16x4 u = *(const f16x4*)(out1 + (size_t)row*256 + lane*4);
    float4 wv = *(const float4*)(wout + lane*4);
    float s = (float)u[0]*wv.x + (float)u[1]*wv.y + (float)u[2]*wv.z + (float)u[3]*wv.w;
    #pragma unroll
    for (int off = 32; off > 0; off >>= 1) s += __shfl_down(s, off, 64);
    if (lane == 0) y[row] = s + bout[0];
}

extern "C" void kernel_launch(void* const* d_in, const int* in_sizes, int n_in,
                              void* d_out, int out_size, void* d_ws, size_t ws_size,
                              hipStream_t stream) {
    const float* x      = (const float*)d_in[0];
    const float* wih_f0 = (const float*)d_in[1];
    const float* whh_f0 = (const float*)d_in[2];
    const float* b_f0   = (const float*)d_in[3];
    const float* wih_r0 = (const float*)d_in[4];
    const float* whh_r0 = (const float*)d_in[5];
    const float* b_r0   = (const float*)d_in[6];
    const float* wih_f1 = (const float*)d_in[7];
    const float* whh_f1 = (const float*)d_in[8];
    const float* b_f1   = (const float*)d_in[9];
    const float* wih_r1 = (const float*)d_in[10];
    const float* whh_r1 = (const float*)d_in[11];
    const float* b_r1   = (const float*)d_in[12];
    const float* w_out  = (const float*)d_in[13];
    const float* b_out  = (const float*)d_in[14];

    const size_t w0N = 512*64, w1N = (size_t)512*256;
    const size_t w0B = w0N*2, w1B = w1N*2;
    const size_t stB = 2*4*4096*4;               // 128 KB rec state
    const size_t hB  = (size_t)SEQ*NB*256*2;     // 67.1 MB per f16 h-buffer
    const size_t fixedB = 4*w0B + 4*w1B + stB;

    const int cand[7] = {2048, 1024, 512, 256, 128, 64, 32};
    int Tc = 0; int tierA = 1;
    for (int i = 0; i < 7 && !Tc; ++i)
        if (fixedB + 3*hB + (size_t)(cand[i]+2)*65536*4 <= ws_size) Tc = cand[i];
    if (!Tc) {
        tierA = 0;
        for (int i = 0; i < 7 && !Tc; ++i)
            if (fixedB + 2*hB + (size_t)(cand[i]+2)*65536*4 <= ws_size) Tc = cand[i];
        if (!Tc) Tc = 32;
    }
    const int nq = SEQ / Tc;

    char* p = (char*)d_ws;
    _Float16* whi0f = (_Float16*)p; p += w0B;
    _Float16* wlo0f = (_Float16*)p; p += w0B;
    _Float16* whi0r = (_Float16*)p; p += w0B;
    _Float16* wlo0r = (_Float16*)p; p += w0B;
    _Float16* whi1f = (_Float16*)p; p += w1B;
    _Float16* wlo1f = (_Float16*)p; p += w1B;
    _Float16* whi1r = (_Float16*)p; p += w1B;
    _Float16* wlo1r = (_Float16*)p; p += w1B;
    float*    state = (float*)p;    p += stB;
    _Float16* out1  = (_Float16*)p; p += hB;
    _Float16* h0hi  = (_Float16*)p; p += hB;
    _Float16* h0lo  = (_Float16*)p; if (tierA) p += hB;
    float*    gx    = (float*)p;

    split_f32<<<(int)((w0N+255)/256), 256, 0, stream>>>(wih_f0, whi0f, wlo0f, (int)w0N);
    split_f32<<<(int)((w0N+255)/256), 256, 0, stream>>>(wih_r0, whi0r, wlo0r, (int)w0N);
    split_f32<<<(int)((w1N+255)/256), 256, 0, stream>>>(wih_f1, whi1f, wlo1f, (int)w1N);
    split_f32<<<(int)((w1N+255)/256), 256, 0, stream>>>(wih_r1, whi1r, wlo1r, (int)w1N);

    for (int q = 0; q < nq; ++q) {
        gemm0<<<dim3(8, Tc, 2), 256, 0, stream>>>(x, whi0f, wlo0f, whi0r, wlo0r,
                                                  b_f0, b_r0, gx, q*Tc);
        if (tierA)
            lstm_rec3<0><<<dim3(4,2), 512, 0, stream>>>(gx, whh_f0, whh_r0, h0hi, h0lo,
                                                        state, q*Tc, Tc, q==0);
        else
            lstm_rec3<1><<<dim3(4,2), 512, 0, stream>>>(gx, whh_f0, whh_r0, h0hi, nullptr,
                                                        state, q*Tc, Tc, q==0);
    }
    for (int q = 0; q < nq; ++q) {
        if (tierA)
            gemm1<1><<<dim3(8, Tc, 2), 256, 0, stream>>>(h0hi, h0lo, whi1f, wlo1f, whi1r, wlo1r,
                                                         b_f1, b_r1, gx, q*Tc);
        else
            gemm1<0><<<dim3(8, Tc, 2), 256, 0, stream>>>(h0hi, h0hi, whi1f, wlo1f, whi1r, wlo1r,
                                                         b_f1, b_r1, gx, q*Tc);
        lstm_rec3<1><<<dim3(4,2), 512, 0, stream>>>(gx, whh_f1, whh_r1, out1, nullptr,
                                                    state, q*Tc, Tc, q==0);
    }
    final_lin<<<SEQ*NB/4, 256, 0, stream>>>(out1, w_out, b_out, (float*)d_out);
}

// Round 8
// 5953.362 us; speedup vs baseline: 1.3374x; 1.1566x over previous
//
#include <hip/hip_runtime.h>
#include <hip/hip_bf16.h>

#define SEQ 2048
#define NB  64

typedef _Float16 f16x8 __attribute__((ext_vector_type(8)));
typedef _Float16 f16x4 __attribute__((ext_vector_type(4)));
typedef float    f32x4 __attribute__((ext_vector_type(4)));

__device__ __forceinline__ float fast_sigmoid(float x) {
    float e = __builtin_amdgcn_exp2f(-1.4426950408889634f * x);
    return __builtin_amdgcn_rcpf(1.f + e);
}
__device__ __forceinline__ float fast_tanh(float x) {
    float e = __builtin_amdgcn_exp2f(2.8853900817779268f * x);
    return fmaf(-2.f, __builtin_amdgcn_rcpf(1.f + e), 1.f);
}

// One dispatch: split all four input-weight matrices f32 -> f16 hi/lo pairs.
__global__ __launch_bounds__(256) void split_all(
    const float* __restrict__ w0f, const float* __restrict__ w0r,
    const float* __restrict__ w1f, const float* __restrict__ w1r,
    _Float16* hi0f, _Float16* lo0f, _Float16* hi0r, _Float16* lo0r,
    _Float16* hi1f, _Float16* lo1f, _Float16* hi1r, _Float16* lo1r)
{
    const int n0 = 512*64, n1 = 512*256;
    int j = blockIdx.x * 256 + threadIdx.x;
    const float* s; _Float16 *hi, *lo;
    if (j < n0)                { s = w0f; hi = hi0f; lo = lo0f; }
    else if ((j -= n0) < n0)   { s = w0r; hi = hi0r; lo = lo0r; }
    else if ((j -= n0) < n1)   { s = w1f; hi = hi1f; lo = lo1f; }
    else if ((j -= n1) < n1)   { s = w1r; hi = hi1r; lo = lo1r; }
    else return;
    float v = s[j];
    _Float16 h = (_Float16)v;
    hi[j] = h;
    lo[j] = (_Float16)(v - (float)h);
}

// gx fragment layout (per chunk step s):
//   off = s*65536 + (dir*4 + bg16)*8192 + gt*256 + lane*4 + reg   (f32)
// = 16x16x32 MFMA C layout: n = gt*16+(lane&15), m = bg16*16+(lane>>4)*4+reg.

// ---------------------------------------------------------------------------
// Recurrence body (round-5 verified structure, bit-identical numerics).
// 8 WGs (4 bg x 2 dir), 512 thr. Wave w: gate tiles gt=8T+w, cells kidx=16w+col.
// PHASE 0: write h as f16 hi+lo planes (feeds gemm1). PHASE 1: hi only (out1).
// ---------------------------------------------------------------------------
template<int PHASE>
__device__ __forceinline__ void rec_body(
    const float* __restrict__ gx,
    const float* __restrict__ Whf, const float* __restrict__ Whr,
    _Float16* __restrict__ o1, _Float16* __restrict__ o2,
    float* __restrict__ state, int tq0, int steps, int first,
    int bg, int dir)
{
    const float* Wh = dir ? Whr : Whf;
    const int tid  = threadIdx.x;
    const int w    = tid >> 6;
    const int lane = tid & 63;
    const int col  = lane & 15;
    const int kg   = lane >> 4;
    const int kidx = 16*w + col;

    f16x8 Bhi[4][4], Blo[4][4];
    #pragma unroll
    for (int T = 0; T < 4; ++T) {
        const float* wr = Wh + (size_t)((8*T + w)*16 + col) * 128;
        #pragma unroll
        for (int ks = 0; ks < 4; ++ks) {
            const float* p4 = wr + ks*32 + kg*8;
            float4 a0 = *(const float4*)p4, a1 = *(const float4*)(p4+4);
            float av[8] = {a0.x,a0.y,a0.z,a0.w,a1.x,a1.y,a1.z,a1.w};
            f16x8 hi, lo;
            #pragma unroll
            for (int e = 0; e < 8; ++e) {
                _Float16 h = (_Float16)av[e];
                hi[e] = h; lo[e] = (_Float16)(av[e] - (float)h);
            }
            Bhi[T][ks] = hi; Blo[T][ks] = lo;
        }
    }

    __shared__ f16x8 HhiA[256], HloA[256], HhiB[256], HloB[256];

    float cr[4], hr[4];
    float* stbase = state + ((size_t)dir*4 + bg) * 4096;
    #pragma unroll
    for (int r = 0; r < 4; ++r) {
        const int m = kg*4 + r;
        float hv = first ? 0.f : stbase[m*128 + kidx];
        float cv = first ? 0.f : stbase[2048 + m*128 + kidx];
        hr[r] = hv; cr[r] = cv;
        _Float16 hhi = (_Float16)hv;
        _Float16 hlo = (_Float16)(hv - (float)hhi);
        const int el = m*128 + (((kidx>>3) ^ m) & 15)*8 + (kidx & 7);
        ((_Float16*)HhiA)[el] = hhi;
        ((_Float16*)HloA)[el] = hlo;
    }
    __syncthreads();

    const float* gxp = gx + (size_t)(dir*4 + bg)*8192 + (size_t)lane*4;

    f32x4 gA[4], gB[4];
    #pragma unroll
    for (int T = 0; T < 4; ++T) {
        gA[T] = *(const f32x4*)(gxp + (8*T + w)*256);
        gB[T] = *(const f32x4*)(gxp + (8*T + w)*256 + 65536);
    }

    auto rec_step = [&](f32x4 (&G)[4], f16x8 (&RHI)[256], f16x8 (&RLO)[256],
                        f16x8 (&WHI)[256], f16x8 (&WLO)[256], int STEP) {
        f16x8 Ah[4], Al[4];
        #pragma unroll
        for (int ks = 0; ks < 4; ++ks) {
            const int u = col*16 + ((ks*4 + kg) ^ col);
            Ah[ks] = RHI[u];
            Al[ks] = RLO[u];
        }
        f32x4 acc0 = G[0], acc1 = G[1], acc2 = G[2], acc3 = G[3];
        #pragma unroll
        for (int T = 0; T < 4; ++T)
            G[T] = *(const f32x4*)(gxp + (8*T + w)*256 + (size_t)(STEP + 2)*65536);
        #pragma unroll
        for (int ks = 0; ks < 4; ++ks) {
            acc0 = __builtin_amdgcn_mfma_f32_16x16x32_f16(Ah[ks], Bhi[0][ks], acc0, 0,0,0);
            acc0 = __builtin_amdgcn_mfma_f32_16x16x32_f16(Al[ks], Bhi[0][ks], acc0, 0,0,0);
            acc0 = __builtin_amdgcn_mfma_f32_16x16x32_f16(Ah[ks], Blo[0][ks], acc0, 0,0,0);
            acc1 = __builtin_amdgcn_mfma_f32_16x16x32_f16(Ah[ks], Bhi[1][ks], acc1, 0,0,0);
            acc1 = __builtin_amdgcn_mfma_f32_16x16x32_f16(Al[ks], Bhi[1][ks], acc1, 0,0,0);
            acc1 = __builtin_amdgcn_mfma_f32_16x16x32_f16(Ah[ks], Blo[1][ks], acc1, 0,0,0);
            acc2 = __builtin_amdgcn_mfma_f32_16x16x32_f16(Ah[ks], Bhi[2][ks], acc2, 0,0,0);
            acc2 = __builtin_amdgcn_mfma_f32_16x16x32_f16(Al[ks], Bhi[2][ks], acc2, 0,0,0);
            acc2 = __builtin_amdgcn_mfma_f32_16x16x32_f16(Ah[ks], Blo[2][ks], acc2, 0,0,0);
            acc3 = __builtin_amdgcn_mfma_f32_16x16x32_f16(Ah[ks], Bhi[3][ks], acc3, 0,0,0);
            acc3 = __builtin_amdgcn_mfma_f32_16x16x32_f16(Al[ks], Bhi[3][ks], acc3, 0,0,0);
            acc3 = __builtin_amdgcn_mfma_f32_16x16x32_f16(Ah[ks], Blo[3][ks], acc3, 0,0,0);
        }
        const int t = dir ? (SEQ-1 - tq0 - STEP) : (tq0 + STEP);
        #pragma unroll
        for (int r = 0; r < 4; ++r) {
            float iv = fast_sigmoid(acc0[r]);
            float fv = fast_sigmoid(acc1[r]);
            float gv = fast_tanh(acc2[r]);
            float ov = fast_sigmoid(acc3[r]);
            float cv = fmaf(fv, cr[r], iv * gv);
            cr[r] = cv;
            float hv = ov * fast_tanh(cv);
            hr[r] = hv;
            _Float16 hhi = (_Float16)hv;
            _Float16 hlo = (_Float16)(hv - (float)hhi);
            const int m = kg*4 + r;
            const int el = m*128 + (((kidx>>3) ^ m) & 15)*8 + (kidx & 7);
            ((_Float16*)WHI)[el] = hhi;
            ((_Float16*)WLO)[el] = hlo;
            const size_t oi = ((size_t)t*NB + (bg*16 + m))*256 + dir*128 + kidx;
            o1[oi] = hhi;                      // fire-and-forget
            if constexpr (PHASE == 0) o2[oi] = hlo;
        }
        asm volatile("s_waitcnt lgkmcnt(0)" ::: "memory");
        __builtin_amdgcn_s_barrier();
        asm volatile("" ::: "memory");
    };

    for (int step = 0; step < steps; step += 2) {
        rec_step(gA, HhiA, HloA, HhiB, HloB, step);
        rec_step(gB, HhiB, HloB, HhiA, HloA, step + 1);
    }

    #pragma unroll
    for (int r = 0; r < 4; ++r) {
        const int m = kg*4 + r;
        stbase[m*128 + kidx] = hr[r];
        stbase[2048 + m*128 + kidx] = cr[r];
    }
}

// ---------------------------------------------------------------------------
// Fused chunk step. blockIdx < nrec: recurrence WG for chunk q (reads gxR).
// blockIdx >= nrec: GEMM WG for chunk q+1 (writes gxW). 512 thr everywhere;
// GEMM WGs = 8 waves covering two time slots (4 waves each, round-5 tiling).
// PHASE 0: gemm0 (A = x f32, K=64). PHASE 1: gemm1 (A = h0 hi/lo, K=256).
// ---------------------------------------------------------------------------
template<int PHASE>
__global__ __launch_bounds__(512, 2) void megastep(
    const void* __restrict__ Agm, const _Float16* __restrict__ AloG,
    const _Float16* __restrict__ whiF, const _Float16* __restrict__ wloF,
    const _Float16* __restrict__ whiR, const _Float16* __restrict__ wloR,
    const float* __restrict__ bF, const float* __restrict__ bR,
    float* __restrict__ gxW,
    const float* __restrict__ gxR,
    const float* __restrict__ Whf, const float* __restrict__ Whr,
    _Float16* __restrict__ o1, _Float16* __restrict__ o2,
    float* __restrict__ state,
    int nrec, int tq0r, int steps, int first,
    int tq0g, int Tc)
{
    const int bid = blockIdx.x;
    if (bid < nrec) {
        rec_body<PHASE>(gxR, Whf, Whr, o1, o2, state, tq0r, steps, first,
                        bid & 3, bid >> 2);
        return;
    }
    // ---- GEMM part (chunk at tq0g) ----
    const int g    = bid - nrec;
    const int nblk = g & 7;
    const int rr   = g >> 3;
    const int half = Tc >> 1;
    const int spair = rr % half;
    const int dir   = rr / half;
    const int tid  = threadIdx.x;
    const int lane = tid & 63;
    const int w8   = tid >> 6;
    const int s    = spair*2 + (w8 >> 2);      // chunk-local time slot
    const int wave = w8 & 3;
    const int t    = dir ? (SEQ - 1 - tq0g - s) : (tq0g + s);
    const _Float16* Whi = dir ? whiR : whiF;
    const _Float16* Wlo = dir ? wloR : wloF;
    const float* bias   = dir ? bR   : bF;
    const int col = lane & 15, kg = lane >> 4;

    if constexpr (PHASE == 0) {
        const float* x = (const float*)Agm;
        const int n0 = nblk * 64;
        f32x4 acc[4] = {{0,0,0,0},{0,0,0,0},{0,0,0,0},{0,0,0,0}};
        #pragma unroll
        for (int ks = 0; ks < 2; ++ks) {
            const float* ar = x + ((size_t)t*NB + wave*16 + col) * 64 + ks*32 + kg*8;
            float4 a0 = *(const float4*)ar;
            float4 a1 = *(const float4*)(ar + 4);
            f16x8 ahi, alo;
            float av[8] = {a0.x,a0.y,a0.z,a0.w,a1.x,a1.y,a1.z,a1.w};
            #pragma unroll
            for (int e = 0; e < 8; ++e) {
                _Float16 h = (_Float16)av[e];
                ahi[e] = h; alo[e] = (_Float16)(av[e] - (float)h);
            }
            #pragma unroll
            for (int nt = 0; nt < 4; ++nt) {
                size_t idx = (size_t)(n0 + nt*16 + col) * 64 + ks*32 + kg*8;
                f16x8 bhi = *(const f16x8*)(Whi + idx);
                f16x8 blo = *(const f16x8*)(Wlo + idx);
                acc[nt] = __builtin_amdgcn_mfma_f32_16x16x32_f16(ahi, bhi, acc[nt], 0,0,0);
                acc[nt] = __builtin_amdgcn_mfma_f32_16x16x32_f16(ahi, blo, acc[nt], 0,0,0);
                acc[nt] = __builtin_amdgcn_mfma_f32_16x16x32_f16(alo, bhi, acc[nt], 0,0,0);
            }
        }
        #pragma unroll
        for (int nt = 0; nt < 4; ++nt) {
            const int n = n0 + nt*16 + col;
            const float bv = bias[n];
            f32x4 v = {acc[nt][0]+bv, acc[nt][1]+bv, acc[nt][2]+bv, acc[nt][3]+bv};
            size_t fi = (size_t)s*65536 + (size_t)(dir*4 + wave)*8192
                      + (size_t)(nblk*4 + nt)*256 + lane*4;
            *(f32x4*)(gxW + fi) = v;
        }
    } else {
        const _Float16* Ahi = (const _Float16*)Agm;
        const int wm = wave >> 1, wn = wave & 1;
        const int n0 = nblk * 64 + wn * 32;
        f32x4 acc[2][2] = {{{0,0,0,0},{0,0,0,0}},{{0,0,0,0},{0,0,0,0}}};
        #pragma unroll
        for (int ks = 0; ks < 8; ++ks) {
            f16x8 ahi[2], alo[2];
            #pragma unroll
            for (int mt = 0; mt < 2; ++mt) {
                const size_t arow = (size_t)t*NB + wm*32 + mt*16 + col;
                ahi[mt] = *(const f16x8*)(Ahi  + arow*256 + ks*32 + kg*8);
                alo[mt] = *(const f16x8*)(AloG + arow*256 + ks*32 + kg*8);
            }
            #pragma unroll
            for (int nt = 0; nt < 2; ++nt) {
                size_t idx = (size_t)(n0 + nt*16 + col) * 256 + ks*32 + kg*8;
                f16x8 bhi = *(const f16x8*)(Whi + idx);
                f16x8 blo = *(const f16x8*)(Wlo + idx);
                #pragma unroll
                for (int mt = 0; mt < 2; ++mt) {
                    acc[mt][nt] = __builtin_amdgcn_mfma_f32_16x16x32_f16(ahi[mt], bhi, acc[mt][nt], 0,0,0);
                    acc[mt][nt] = __builtin_amdgcn_mfma_f32_16x16x32_f16(ahi[mt], blo, acc[mt][nt], 0,0,0);
                    acc[mt][nt] = __builtin_amdgcn_mfma_f32_16x16x32_f16(alo[mt], bhi, acc[mt][nt], 0,0,0);
                }
            }
        }
        #pragma unroll
        for (int mt = 0; mt < 2; ++mt)
            #pragma unroll
            for (int nt = 0; nt < 2; ++nt) {
                const int n = n0 + nt*16 + col;
                const float bv = bias[n];
                f32x4 v = {acc[mt][nt][0]+bv, acc[mt][nt][1]+bv,
                           acc[mt][nt][2]+bv, acc[mt][nt][3]+bv};
                size_t fi = (size_t)s*65536 + (size_t)(dir*4 + (wm*2+mt))*8192
                          + (size_t)(nblk*4 + wn*2 + nt)*256 + lane*4;
                *(f32x4*)(gxW + fi) = v;
            }
    }
}

// ---------------------------------------------------------------------------
// Head: y[m] = sum_j out1[m][j]*w_out[j] + b_out. One wave per row.
// ---------------------------------------------------------------------------
__global__ __launch_bounds__(256) void final_lin(
    const _Float16* __restrict__ out1,
    const float* __restrict__ wout, const float* __restrict__ bout,
    float* __restrict__ y)
{
    const int lane = threadIdx.x & 63;
    const int wave = threadIdx.x >> 6;
    const int row  = blockIdx.x * 4 + wave;
    f16x4 u = *(const f16x4*)(out1 + (size_t)row*256 + lane*4);
    float4 wv = *(const float4*)(wout + lane*4);
    float s = (float)u[0]*wv.x + (float)u[1]*wv.y + (float)u[2]*wv.z + (float)u[3]*wv.w;
    #pragma unroll
    for (int off = 32; off > 0; off >>= 1) s += __shfl_down(s, off, 64);
    if (lane == 0) y[row] = s + bout[0];
}

extern "C" void kernel_launch(void* const* d_in, const int* in_sizes, int n_in,
                              void* d_out, int out_size, void* d_ws, size_t ws_size,
                              hipStream_t stream) {
    const float* x      = (const float*)d_in[0];
    const float* wih_f0 = (const float*)d_in[1];
    const float* whh_f0 = (const float*)d_in[2];
    const float* b_f0   = (const float*)d_in[3];
    const float* wih_r0 = (const float*)d_in[4];
    const float* whh_r0 = (const float*)d_in[5];
    const float* b_r0   = (const float*)d_in[6];
    const float* wih_f1 = (const float*)d_in[7];
    const float* whh_f1 = (const float*)d_in[8];
    const float* b_f1   = (const float*)d_in[9];
    const float* wih_r1 = (const float*)d_in[10];
    const float* whh_r1 = (const float*)d_in[11];
    const float* b_r1   = (const float*)d_in[12];
    const float* w_out  = (const float*)d_in[13];
    const float* b_out  = (const float*)d_in[14];

    const size_t w0N = 512*64, w1N = (size_t)512*256;
    const size_t w0B = w0N*2, w1B = w1N*2;
    const size_t stB = 2*4*4096*4;                 // 128 KB rec state
    const size_t hB  = (size_t)SEQ*NB*256*2;       // 67.1 MB per f16 h-plane
    const size_t gxStepB = 65536ull*4;             // 256 KB per gx step
    const size_t fixedB = 4*w0B + 4*w1B + stB;

    // Double-buffered gx (fused pipeline); 3 h-planes (out1, h0hi, h0lo).
    const int cand[4] = {256, 128, 64, 32};
    int Tc = 32;
    for (int i = 0; i < 4; ++i)
        if (fixedB + 3*hB + 2*(size_t)(cand[i]+2)*gxStepB <= ws_size) { Tc = cand[i]; break; }
    const int nq = SEQ / Tc;

    char* p = (char*)d_ws;
    _Float16* whi0f = (_Float16*)p; p += w0B;
    _Float16* wlo0f = (_Float16*)p; p += w0B;
    _Float16* whi0r = (_Float16*)p; p += w0B;
    _Float16* wlo0r = (_Float16*)p; p += w0B;
    _Float16* whi1f = (_Float16*)p; p += w1B;
    _Float16* wlo1f = (_Float16*)p; p += w1B;
    _Float16* whi1r = (_Float16*)p; p += w1B;
    _Float16* wlo1r = (_Float16*)p; p += w1B;
    float*    state = (float*)p;    p += stB;
    _Float16* out1  = (_Float16*)p; p += hB;
    _Float16* h0hi  = (_Float16*)p; p += hB;
    _Float16* h0lo  = (_Float16*)p; p += hB;
    float*    gx0   = (float*)p;    p += (size_t)(Tc+2)*gxStepB;
    float*    gx1   = (float*)p;

    split_all<<<(int)((2*w0N + 2*w1N + 255)/256), 256, 0, stream>>>(
        wih_f0, wih_r0, wih_f1, wih_r1,
        whi0f, wlo0f, whi0r, wlo0r, whi1f, wlo1f, whi1r, wlo1r);

    const int ngemm = 8 * Tc;   // 8 nblk * (Tc/2) spairs * 2 dirs
    float* gxb[2] = {gx0, gx1};

    // ---- Layer 0: gemm0 prologue, then fused rec-L0(q) || gemm0(q+1) ----
    megastep<0><<<ngemm, 512, 0, stream>>>(
        x, nullptr, whi0f, wlo0f, whi0r, wlo0r, b_f0, b_r0,
        gxb[0], nullptr, nullptr, nullptr, nullptr, nullptr, nullptr,
        0, 0, 0, 0, 0, Tc);
    for (int q = 0; q < nq; ++q) {
        const int nxt = (q + 1 < nq);
        megastep<0><<<8 + (nxt ? ngemm : 0), 512, 0, stream>>>(
            x, nullptr, whi0f, wlo0f, whi0r, wlo0r, b_f0, b_r0,
            gxb[(q+1)&1], gxb[q&1], whh_f0, whh_r0, h0hi, h0lo, state,
            8, q*Tc, Tc, q==0, (q+1)*Tc, Tc);
    }
    // ---- Layer 1: gemm1 prologue, then fused rec-L1(q) || gemm1(q+1) ----
    megastep<1><<<ngemm, 512, 0, stream>>>(
        h0hi, h0lo, whi1f, wlo1f, whi1r, wlo1r, b_f1, b_r1,
        gxb[0], nullptr, nullptr, nullptr, nullptr, nullptr, nullptr,
        0, 0, 0, 0, 0, Tc);
    for (int q = 0; q < nq; ++q) {
        const int nxt = (q + 1 < nq);
        megastep<1><<<8 + (nxt ? ngemm : 0), 512, 0, stream>>>(
            h0hi, h0lo, whi1f, wlo1f, whi1r, wlo1r, b_f1, b_r1,
            gxb[(q+1)&1], gxb[q&1], whh_f1, whh_r1, out1, nullptr, state,
            8, q*Tc, Tc, q==0, (q+1)*Tc, Tc);
    }
    final_lin<<<SEQ*NB/4, 256, 0, stream>>>(out1, w_out, b_out, (float*)d_out);
}

// Round 9
// 5657.265 us; speedup vs baseline: 1.4074x; 1.0523x over previous
//
#include <hip/hip_runtime.h>
#include <hip/hip_bf16.h>

#define SEQ 2048
#define NB  64

typedef _Float16 f16x8 __attribute__((ext_vector_type(8)));
typedef _Float16 f16x4 __attribute__((ext_vector_type(4)));
typedef float    f32x4 __attribute__((ext_vector_type(4)));

__device__ __forceinline__ float fast_sigmoid(float x) {
    float e = __builtin_amdgcn_exp2f(-1.4426950408889634f * x);
    return __builtin_amdgcn_rcpf(1.f + e);
}
__device__ __forceinline__ float fast_tanh(float x) {
    float e = __builtin_amdgcn_exp2f(2.8853900817779268f * x);
    return fmaf(-2.f, __builtin_amdgcn_rcpf(1.f + e), 1.f);
}

// Split 8 consecutive f32 into f16 hi/lo fragments (hi+lo ~ 22 mantissa bits).
__device__ __forceinline__ void split8(const float* p4, f16x8& hi, f16x8& lo) {
    float4 a0 = *(const float4*)p4, a1 = *(const float4*)(p4 + 4);
    float av[8] = {a0.x,a0.y,a0.z,a0.w,a1.x,a1.y,a1.z,a1.w};
    #pragma unroll
    for (int e = 0; e < 8; ++e) {
        _Float16 h = (_Float16)av[e];
        hi[e] = h; lo[e] = (_Float16)(av[e] - (float)h);
    }
}

// gx fragment layout (per chunk step s):
//   off = s*65536 + (dir*4 + bg16)*8192 + gt*256 + lane*4 + reg   (f32)
// = 16x16x32 MFMA C layout: n = gt*16+(lane&15), m = bg16*16+(lane>>4)*4+reg.

// ---------------------------------------------------------------------------
// Recurrence body (round-5/8 verified structure, bit-identical numerics).
// 8 WGs (4 bg x 2 dir), 512 thr. Wave w: gate tiles gt=8T+w, cells kidx=16w+col.
// s_setprio(2): rec waves outrank co-resident gemm waves on the CU scheduler.
// PHASE 0: write h as f16 hi+lo planes (feeds gemm1). PHASE 1: hi only (out1).
// ---------------------------------------------------------------------------
template<int PHASE>
__device__ __forceinline__ void rec_body(
    const float* __restrict__ gx,
    const float* __restrict__ Whf, const float* __restrict__ Whr,
    _Float16* __restrict__ o1, _Float16* __restrict__ o2,
    float* __restrict__ state, int tq0, int steps, int first,
    int bg, int dir)
{
    __builtin_amdgcn_s_setprio(2);     // protect the serial critical path
    const float* Wh = dir ? Whr : Whf;
    const int tid  = threadIdx.x;
    const int w    = tid >> 6;
    const int lane = tid & 63;
    const int col  = lane & 15;
    const int kg   = lane >> 4;
    const int kidx = 16*w + col;

    f16x8 Bhi[4][4], Blo[4][4];
    #pragma unroll
    for (int T = 0; T < 4; ++T) {
        const float* wr = Wh + (size_t)((8*T + w)*16 + col) * 128;
        #pragma unroll
        for (int ks = 0; ks < 4; ++ks)
            split8(wr + ks*32 + kg*8, Bhi[T][ks], Blo[T][ks]);
    }

    __shared__ f16x8 HhiA[256], HloA[256], HhiB[256], HloB[256];

    float cr[4], hr[4];
    float* stbase = state + ((size_t)dir*4 + bg) * 4096;
    #pragma unroll
    for (int r = 0; r < 4; ++r) {
        const int m = kg*4 + r;
        float hv = first ? 0.f : stbase[m*128 + kidx];
        float cv = first ? 0.f : stbase[2048 + m*128 + kidx];
        hr[r] = hv; cr[r] = cv;
        _Float16 hhi = (_Float16)hv;
        _Float16 hlo = (_Float16)(hv - (float)hhi);
        const int el = m*128 + (((kidx>>3) ^ m) & 15)*8 + (kidx & 7);
        ((_Float16*)HhiA)[el] = hhi;
        ((_Float16*)HloA)[el] = hlo;
    }
    __syncthreads();

    const float* gxp = gx + (size_t)(dir*4 + bg)*8192 + (size_t)lane*4;

    f32x4 gA[4], gB[4];
    #pragma unroll
    for (int T = 0; T < 4; ++T) {
        gA[T] = *(const f32x4*)(gxp + (8*T + w)*256);
        gB[T] = *(const f32x4*)(gxp + (8*T + w)*256 + 65536);
    }

    auto rec_step = [&](f32x4 (&G)[4], f16x8 (&RHI)[256], f16x8 (&RLO)[256],
                        f16x8 (&WHI)[256], f16x8 (&WLO)[256], int STEP) {
        f16x8 Ah[4], Al[4];
        #pragma unroll
        for (int ks = 0; ks < 4; ++ks) {
            const int u = col*16 + ((ks*4 + kg) ^ col);
            Ah[ks] = RHI[u];
            Al[ks] = RLO[u];
        }
        f32x4 acc0 = G[0], acc1 = G[1], acc2 = G[2], acc3 = G[3];
        // prefetch 2 steps ahead, clamped (no pad buffer; tail prefetch unused)
        const int ps = (STEP + 2 < steps) ? (STEP + 2) : (steps - 1);
        #pragma unroll
        for (int T = 0; T < 4; ++T)
            G[T] = *(const f32x4*)(gxp + (8*T + w)*256 + (size_t)ps*65536);
        #pragma unroll
        for (int ks = 0; ks < 4; ++ks) {
            acc0 = __builtin_amdgcn_mfma_f32_16x16x32_f16(Ah[ks], Bhi[0][ks], acc0, 0,0,0);
            acc0 = __builtin_amdgcn_mfma_f32_16x16x32_f16(Al[ks], Bhi[0][ks], acc0, 0,0,0);
            acc0 = __builtin_amdgcn_mfma_f32_16x16x32_f16(Ah[ks], Blo[0][ks], acc0, 0,0,0);
            acc1 = __builtin_amdgcn_mfma_f32_16x16x32_f16(Ah[ks], Bhi[1][ks], acc1, 0,0,0);
            acc1 = __builtin_amdgcn_mfma_f32_16x16x32_f16(Al[ks], Bhi[1][ks], acc1, 0,0,0);
            acc1 = __builtin_amdgcn_mfma_f32_16x16x32_f16(Ah[ks], Blo[1][ks], acc1, 0,0,0);
            acc2 = __builtin_amdgcn_mfma_f32_16x16x32_f16(Ah[ks], Bhi[2][ks], acc2, 0,0,0);
            acc2 = __builtin_amdgcn_mfma_f32_16x16x32_f16(Al[ks], Bhi[2][ks], acc2, 0,0,0);
            acc2 = __builtin_amdgcn_mfma_f32_16x16x32_f16(Ah[ks], Blo[2][ks], acc2, 0,0,0);
            acc3 = __builtin_amdgcn_mfma_f32_16x16x32_f16(Ah[ks], Bhi[3][ks], acc3, 0,0,0);
            acc3 = __builtin_amdgcn_mfma_f32_16x16x32_f16(Al[ks], Bhi[3][ks], acc3, 0,0,0);
            acc3 = __builtin_amdgcn_mfma_f32_16x16x32_f16(Ah[ks], Blo[3][ks], acc3, 0,0,0);
        }
        const int t = dir ? (SEQ-1 - tq0 - STEP) : (tq0 + STEP);
        #pragma unroll
        for (int r = 0; r < 4; ++r) {
            float iv = fast_sigmoid(acc0[r]);
            float fv = fast_sigmoid(acc1[r]);
            float gv = fast_tanh(acc2[r]);
            float ov = fast_sigmoid(acc3[r]);
            float cv = fmaf(fv, cr[r], iv * gv);
            cr[r] = cv;
            float hv = ov * fast_tanh(cv);
            hr[r] = hv;
            _Float16 hhi = (_Float16)hv;
            _Float16 hlo = (_Float16)(hv - (float)hhi);
            const int m = kg*4 + r;
            const int el = m*128 + (((kidx>>3) ^ m) & 15)*8 + (kidx & 7);
            ((_Float16*)WHI)[el] = hhi;
            ((_Float16*)WLO)[el] = hlo;
            const size_t oi = ((size_t)t*NB + (bg*16 + m))*256 + dir*128 + kidx;
            o1[oi] = hhi;                      // fire-and-forget
            if constexpr (PHASE == 0) o2[oi] = hlo;
        }
        asm volatile("s_waitcnt lgkmcnt(0)" ::: "memory");
        __builtin_amdgcn_s_barrier();
        asm volatile("" ::: "memory");
    };

    for (int step = 0; step < steps; step += 2) {
        rec_step(gA, HhiA, HloA, HhiB, HloB, step);
        rec_step(gB, HhiB, HloB, HhiA, HloA, step + 1);
    }

    #pragma unroll
    for (int r = 0; r < 4; ++r) {
        const int m = kg*4 + r;
        stbase[m*128 + kidx] = hr[r];
        stbase[2048 + m*128 + kidx] = cr[r];
    }
    __builtin_amdgcn_s_setprio(0);
}

// ---------------------------------------------------------------------------
// Fused chunk step. blockIdx < nrec: recurrence WG for chunk q (reads gxR).
// blockIdx >= nrec: GEMM WG for chunk q+1 (writes gxW). 512 thr everywhere;
// GEMM WGs: 8 waves covering two time slots (4 waves each). Input weights are
// read as f32 and split to f16 hi/lo inline (identical values to pre-split).
// PHASE 0: gemm0 (A = x f32, K=64). PHASE 1: gemm1 (A = h0 hi/lo, K=256).
// ---------------------------------------------------------------------------
template<int PHASE>
__global__ __launch_bounds__(512, 2) void megastep(
    const void* __restrict__ Agm, const _Float16* __restrict__ AloG,
    const float* __restrict__ WgF, const float* __restrict__ WgR,
    const float* __restrict__ bF, const float* __restrict__ bR,
    float* __restrict__ gxW,
    const float* __restrict__ gxR,
    const float* __restrict__ Whf, const float* __restrict__ Whr,
    _Float16* __restrict__ o1, _Float16* __restrict__ o2,
    float* __restrict__ state,
    int nrec, int tq0r, int steps, int first,
    int tq0g)
{
    const int bid = blockIdx.x;
    if (bid < nrec) {
        rec_body<PHASE>(gxR, Whf, Whr, o1, o2, state, tq0r, steps, first,
                        bid & 3, bid >> 2);
        return;
    }
    // ---- GEMM part (chunk at tq0g) ----
    const int g    = bid - nrec;
    const int nblk = g & 7;
    const int rr   = g >> 3;
    const int half = steps >> 1;
    const int spair = rr % half;
    const int dir   = rr / half;
    const int tid  = threadIdx.x;
    const int lane = tid & 63;
    const int w8   = tid >> 6;
    const int s    = spair*2 + (w8 >> 2);      // chunk-local time slot
    const int wave = w8 & 3;
    const int t    = dir ? (SEQ - 1 - tq0g - s) : (tq0g + s);
    const float* W      = dir ? WgR : WgF;
    const float* bias   = dir ? bR  : bF;
    const int col = lane & 15, kg = lane >> 4;

    if constexpr (PHASE == 0) {
        const float* x = (const float*)Agm;
        const int n0 = nblk * 64;
        f32x4 acc[4] = {{0,0,0,0},{0,0,0,0},{0,0,0,0},{0,0,0,0}};
        #pragma unroll
        for (int ks = 0; ks < 2; ++ks) {
            f16x8 ahi, alo;
            split8(x + ((size_t)t*NB + wave*16 + col) * 64 + ks*32 + kg*8, ahi, alo);
            #pragma unroll
            for (int nt = 0; nt < 4; ++nt) {
                f16x8 bhi, blo;
                split8(W + (size_t)(n0 + nt*16 + col) * 64 + ks*32 + kg*8, bhi, blo);
                acc[nt] = __builtin_amdgcn_mfma_f32_16x16x32_f16(ahi, bhi, acc[nt], 0,0,0);
                acc[nt] = __builtin_amdgcn_mfma_f32_16x16x32_f16(ahi, blo, acc[nt], 0,0,0);
                acc[nt] = __builtin_amdgcn_mfma_f32_16x16x32_f16(alo, bhi, acc[nt], 0,0,0);
            }
        }
        #pragma unroll
        for (int nt = 0; nt < 4; ++nt) {
            const int n = n0 + nt*16 + col;
            const float bv = bias[n];
            f32x4 v = {acc[nt][0]+bv, acc[nt][1]+bv, acc[nt][2]+bv, acc[nt][3]+bv};
            size_t fi = (size_t)s*65536 + (size_t)(dir*4 + wave)*8192
                      + (size_t)(nblk*4 + nt)*256 + lane*4;
            *(f32x4*)(gxW + fi) = v;
        }
    } else {
        const _Float16* Ahi = (const _Float16*)Agm;
        const int wm = wave >> 1, wn = wave & 1;
        const int n0 = nblk * 64 + wn * 32;
        f32x4 acc[2][2] = {{{0,0,0,0},{0,0,0,0}},{{0,0,0,0},{0,0,0,0}}};
        #pragma unroll
        for (int ks = 0; ks < 8; ++ks) {
            f16x8 ahi[2], alo[2];
            #pragma unroll
            for (int mt = 0; mt < 2; ++mt) {
                const size_t arow = (size_t)t*NB + wm*32 + mt*16 + col;
                ahi[mt] = *(const f16x8*)(Ahi  + arow*256 + ks*32 + kg*8);
                alo[mt] = *(const f16x8*)(AloG + arow*256 + ks*32 + kg*8);
            }
            #pragma unroll
            for (int nt = 0; nt < 2; ++nt) {
                f16x8 bhi, blo;
                split8(W + (size_t)(n0 + nt*16 + col) * 256 + ks*32 + kg*8, bhi, blo);
                #pragma unroll
                for (int mt = 0; mt < 2; ++mt) {
                    acc[mt][nt] = __builtin_amdgcn_mfma_f32_16x16x32_f16(ahi[mt], bhi, acc[mt][nt], 0,0,0);
                    acc[mt][nt] = __builtin_amdgcn_mfma_f32_16x16x32_f16(ahi[mt], blo, acc[mt][nt], 0,0,0);
                    acc[mt][nt] = __builtin_amdgcn_mfma_f32_16x16x32_f16(alo[mt], bhi, acc[mt][nt], 0,0,0);
                }
            }
        }
        #pragma unroll
        for (int mt = 0; mt < 2; ++mt)
            #pragma unroll
            for (int nt = 0; nt < 2; ++nt) {
                const int n = n0 + nt*16 + col;
                const float bv = bias[n];
                f32x4 v = {acc[mt][nt][0]+bv, acc[mt][nt][1]+bv,
                           acc[mt][nt][2]+bv, acc[mt][nt][3]+bv};
                size_t fi = (size_t)s*65536 + (size_t)(dir*4 + (wm*2+mt))*8192
                          + (size_t)(nblk*4 + wn*2 + nt)*256 + lane*4;
                *(f32x4*)(gxW + fi) = v;
            }
    }
}

// ---------------------------------------------------------------------------
// Head: y[m] = sum_j out1[m][j]*w_out[j] + b_out. One wave per row.
// Overwrites ALL of d_out (which also served as rec-state scratch).
// ---------------------------------------------------------------------------
__global__ __launch_bounds__(256) void final_lin(
    const _Float16* __restrict__ out1,
    const float* __restrict__ wout, const float* __restrict__ bout,
    float* __restrict__ y)
{
    const int lane = threadIdx.x & 63;
    const int wave = threadIdx.x >> 6;
    const int row  = blockIdx.x * 4 + wave;
    f16x4 u = *(const f16x4*)(out1 + (size_t)row*256 + lane*4);
    float4 wv = *(const float4*)(wout + lane*4);
    float s = (float)u[0]*wv.x + (float)u[1]*wv.y + (float)u[2]*wv.z + (float)u[3]*wv.w;
    #pragma unroll
    for (int off = 32; off > 0; off >>= 1) s += __shfl_down(s, off, 64);
    if (lane == 0) y[row] = s + bout[0];
}

extern "C" void kernel_launch(void* const* d_in, const int* in_sizes, int n_in,
                              void* d_out, int out_size, void* d_ws, size_t ws_size,
                              hipStream_t stream) {
    const float* x      = (const float*)d_in[0];
    const float* wih_f0 = (const float*)d_in[1];
    const float* whh_f0 = (const float*)d_in[2];
    const float* b_f0   = (const float*)d_in[3];
    const float* wih_r0 = (const float*)d_in[4];
    const float* whh_r0 = (const float*)d_in[5];
    const float* b_r0   = (const float*)d_in[6];
    const float* wih_f1 = (const float*)d_in[7];
    const float* whh_f1 = (const float*)d_in[8];
    const float* b_f1   = (const float*)d_in[9];
    const float* wih_r1 = (const float*)d_in[10];
    const float* whh_r1 = (const float*)d_in[11];
    const float* b_r1   = (const float*)d_in[12];
    const float* w_out  = (const float*)d_in[13];
    const float* b_out  = (const float*)d_in[14];

    const size_t hB      = (size_t)SEQ*NB*256*2;   // 67.1 MB per f16 h-plane
    const size_t gxStepB = 65536ull*4;             // 256 KB per gx step

    // Workspace: h0hi | h0lo | out1 | gx0 | gx1. rec state lives in d_out
    // (512 KB; final_lin overwrites all of it at the end).
    const int cand[5] = {256, 128, 64, 32, 16};
    int Tc = 16;
    for (int i = 0; i < 5; ++i)
        if (3*hB + 2*(size_t)cand[i]*gxStepB <= ws_size) { Tc = cand[i]; break; }
    const int nq = SEQ / Tc;

    char* p = (char*)d_ws;
    _Float16* h0hi = (_Float16*)p; p += hB;
    _Float16* h0lo = (_Float16*)p; p += hB;
    _Float16* out1 = (_Float16*)p; p += hB;
    float*    gx0  = (float*)p;    p += (size_t)Tc*gxStepB;
    float*    gx1  = (float*)p;
    float*    state = (float*)d_out;               // 128 KB of the 512 KB out buf

    const int ngemm = 8 * Tc;
    float* gxb[2] = {gx0, gx1};

    // ---- Layer 0: gemm0 prologue, then fused rec-L0(q) || gemm0(q+1) ----
    megastep<0><<<ngemm, 512, 0, stream>>>(
        x, nullptr, wih_f0, wih_r0, b_f0, b_r0,
        gxb[0], nullptr, nullptr, nullptr, nullptr, nullptr, nullptr,
        0, 0, Tc, 0, 0);
    for (int q = 0; q < nq; ++q) {
        const int nxt = (q + 1 < nq);
        megastep<0><<<8 + (nxt ? ngemm : 0), 512, 0, stream>>>(
            x, nullptr, wih_f0, wih_r0, b_f0, b_r0,
            gxb[(q+1)&1], gxb[q&1], whh_f0, whh_r0, h0hi, h0lo, state,
            8, q*Tc, Tc, q==0, (q+1)*Tc);
    }
    // ---- Layer 1: gemm1 prologue, then fused rec-L1(q) || gemm1(q+1) ----
    megastep<1><<<ngemm, 512, 0, stream>>>(
        h0hi, h0lo, wih_f1, wih_r1, b_f1, b_r1,
        gxb[0], nullptr, nullptr, nullptr, nullptr, nullptr, nullptr,
        0, 0, Tc, 0, 0);
    for (int q = 0; q < nq; ++q) {
        const int nxt = (q + 1 < nq);
        megastep<1><<<8 + (nxt ? ngemm : 0), 512, 0, stream>>>(
            h0hi, h0lo, wih_f1, wih_r1, b_f1, b_r1,
            gxb[(q+1)&1], gxb[q&1], whh_f1, whh_r1, out1, nullptr, state,
            8, q*Tc, Tc, q==0, (q+1)*Tc);
    }
    final_lin<<<SEQ*NB/4, 256, 0, stream>>>(out1, w_out, b_out, (float*)d_out);
}